// Round 1
// baseline (111.417 us; speedup 1.0000x reference)
//
#include <hip/hip_runtime.h>

// Hamiltonian flow, separable H = sum(0.5 p^2 + 0.5 q^2 + 0.25 q^4):
//   dq/dt = dH/dp = p
//   dp/dt = -dH/dq = -(q + q^3)
// Each (q,p) pair is independent -> one thread per pair, 255 RK4 steps in
// registers. All negations folded into FMA constants.

__global__ __launch_bounds__(256) void HamiltonianFlow_23957327577411_kernel(
    const float2* __restrict__ x0, float2* __restrict__ out, int n)
{
    int i = blockIdx.x * blockDim.x + threadIdx.x;
    if (i >= n) return;

    float2 v = x0[i];
    float q = v.x;
    float p = v.y;

    const float dt  = (float)(10.0 / 255.0);   // (FINAL_T-INITIAL_T)/(NUM_STEPS-1)
    const float hdt = 0.5f * dt;
    const float dt6 = dt * (1.0f / 6.0f);

    // 255 RK4 steps; unroll-by-5 amortizes loop overhead (255 = 5*51)
    // without full-unroll I-cache blowup.
    #pragma unroll 5
    for (int s = 0; s < 255; ++s) {
        // m_i = q_i + q_i^3  (so k_i for p is -m_i; k_i for q is the p value)
        float u1 = q * q;
        float m1 = fmaf(u1, q, q);          // q + q^3
        float qa = fmaf(hdt, p, q);         // x + 0.5 dt k1  (q comp)
        float pa = fmaf(-hdt, m1, p);       //                (p comp)

        float u2 = qa * qa;
        float m2 = fmaf(u2, qa, qa);
        float qb = fmaf(hdt, pa, q);        // x + 0.5 dt k2
        float pb = fmaf(-hdt, m2, p);

        float u3 = qb * qb;
        float m3 = fmaf(u3, qb, qb);
        float qc = fmaf(dt, pb, q);         // x + dt k3
        float pc = fmaf(-dt, m3, p);

        float u4 = qc * qc;
        float m4 = fmaf(u4, qc, qc);

        // q_next = q + dt/6 * (p + 2 pa + 2 pb + pc)
        float sq = fmaf(2.0f, pa, p);
        sq = fmaf(2.0f, pb, sq);
        sq += pc;
        q = fmaf(dt6, sq, q);

        // p_next = p - dt/6 * (m1 + 2 m2 + 2 m3 + m4)
        float sp = fmaf(2.0f, m2, m1);
        sp = fmaf(2.0f, m3, sp);
        sp += m4;
        p = fmaf(-dt6, sp, p);
    }

    out[i] = make_float2(q, p);
}

extern "C" void kernel_launch(void* const* d_in, const int* in_sizes, int n_in,
                              void* d_out, int out_size, void* d_ws, size_t ws_size,
                              hipStream_t stream) {
    const float2* x0 = (const float2*)d_in[0];
    float2* out = (float2*)d_out;
    int n = in_sizes[0] / 2;          // number of (q,p) pairs = 4096*64 = 262144
    int block = 256;
    int grid = (n + block - 1) / block;
    HamiltonianFlow_23957327577411_kernel<<<grid, block, 0, stream>>>(x0, out, n);
}